// Round 4
// baseline (14120.361 us; speedup 1.0000x reference)
//
#include <hip/hip_runtime.h>
#include <math.h>

#define TT   128
#define BSZ  256
#define IDIM 256
#define CDIM 512
#define NN   128
#define MM   64
#define KTOT 832
#define GJ   2048
#define ODIM 576
#define OC   268

#define NKB1 26            // K-blocks of 32 for gates GEMM (832/32)
#define NJT1 32            // j-tiles of 16 across 512
#define NKB2 16            // K-blocks for heads GEMM (512/32)
#define NJT2 17            // j-tiles of 16 across 272 (268 padded)
#define NBLK 256

typedef __attribute__((ext_vector_type(8))) short s16x8;
typedef __attribute__((ext_vector_type(4))) float f32x4;
typedef unsigned short ush;
#define MFMA __builtin_amdgcn_mfma_f32_16x16x32_bf16

__device__ __forceinline__ float sigmoidf_(float x) { return 1.0f / (1.0f + expf(-x)); }
__device__ __forceinline__ float softplusf_(float x) {
    return (x > 0.f) ? (x + log1pf(expf(-x))) : log1pf(expf(x));
}
__device__ __forceinline__ ush f2bf(float f) {
    unsigned int u = __builtin_bit_cast(unsigned int, f);
    u += 0x7FFFu + ((u >> 16) & 1u);
    return (ush)(u >> 16);
}
__device__ __forceinline__ float bf2f(ush b) {
    unsigned int u = ((unsigned int)b) << 16;
    return __builtin_bit_cast(float, u);
}
__device__ __forceinline__ void split2(float v, ush& h, ush& lo) {
    h = f2bf(v);
    lo = f2bf(v - bf2f(h));
}

// ---------------- prep: pack gates weights into MFMA fragment order, split hi/lo ----------------
__global__ void k_packB1(const float* __restrict__ W_ih, const float* __restrict__ W_hh,
                         const float* __restrict__ b_ih, const float* __restrict__ b_hh,
                         ush* __restrict__ Bh, ush* __restrict__ Bl, float* __restrict__ bias)
{
    const int total = NKB1 * NJT1 * 4 * 64 * 8;
    for (int idx = blockIdx.x * 256 + threadIdx.x; idx < total + GJ; idx += gridDim.x * 256) {
        if (idx < total) {
            int e  = idx & 7;
            int l  = (idx >> 3) & 63;
            int g  = (idx >> 9) & 3;
            int jt = (idx >> 11) & 31;
            int kb = idx >> 16;
            int k  = kb * 32 + ((l >> 4) << 3) + e;
            int n  = g * 512 + jt * 16 + (l & 15);
            float v = (k < 320) ? W_ih[n * 320 + k] : W_hh[n * 512 + (k - 320)];
            ush h_, l_;
            split2(v, h_, l_);
            Bh[idx] = h_; Bl[idx] = l_;
        } else {
            int j = idx - total;
            bias[j] = b_ih[j] + b_hh[j];
        }
    }
}

// ---------------- prep: pack head weights, split hi/lo ----------------
__global__ void k_packB2(const float* __restrict__ rW, const float* __restrict__ rb,
                         const float* __restrict__ wW, const float* __restrict__ wb,
                         ush* __restrict__ Bh, ush* __restrict__ Bl, float* __restrict__ bias2)
{
    const int total = NKB2 * NJT2 * 64 * 8;
    for (int idx = blockIdx.x * 256 + threadIdx.x; idx < total + NJT2 * 16; idx += gridDim.x * 256) {
        if (idx < total) {
            int e   = idx & 7;
            int l   = (idx >> 3) & 63;
            int q   = idx >> 9;           // kb*17 + jt
            int jt  = q % 17;
            int kb  = q / 17;
            int k   = kb * 32 + ((l >> 4) << 3) + e;
            int col = jt * 16 + (l & 15);
            float v = 0.f;
            if (col < 70)       v = rW[k * 70 + col];
            else if (col < OC)  v = wW[k * 198 + (col - 70)];
            ush h_, l_;
            split2(v, h_, l_);
            Bh[idx] = h_; Bl[idx] = l_;
        } else {
            int col = idx - total;
            bias2[col] = (col < 70) ? rb[col] : ((col < OC) ? wb[col - 70] : 0.f);
        }
    }
}

// ---------------- barrier state init (re-run every launch; ws is not re-poisoned) ----------------
__global__ void k_barinit(unsigned* __restrict__ bar) {
    for (int i = threadIdx.x; i < 160; i += 64) bar[i] = 0u;
}

// Two-level grid barrier: 8 group counters (64B apart) + root + generation.
// bar[g*16] g<8: group counters; bar[128]: root; bar[144]: gen.
__device__ __forceinline__ void gridbar(unsigned* bar, int bid) {
    __syncthreads();
    if (threadIdx.x == 0) {
        __threadfence();   // device-scope release of all prior writes
        unsigned g = __hip_atomic_load(&bar[144], __ATOMIC_RELAXED, __HIP_MEMORY_SCOPE_AGENT);
        int grp = bid >> 5;
        unsigned old = __hip_atomic_fetch_add(&bar[grp * 16], 1u, __ATOMIC_ACQ_REL, __HIP_MEMORY_SCOPE_AGENT);
        if (old == 31u) {
            unsigned r = __hip_atomic_fetch_add(&bar[128], 1u, __ATOMIC_ACQ_REL, __HIP_MEMORY_SCOPE_AGENT);
            if (r == 7u) {
                __hip_atomic_store(&bar[128], 0u, __ATOMIC_RELAXED, __HIP_MEMORY_SCOPE_AGENT);
                for (int i = 0; i < 8; ++i)
                    __hip_atomic_store(&bar[i * 16], 0u, __ATOMIC_RELAXED, __HIP_MEMORY_SCOPE_AGENT);
                __hip_atomic_store(&bar[144], g + 1u, __ATOMIC_RELEASE, __HIP_MEMORY_SCOPE_AGENT);
            } else {
                while (__hip_atomic_load(&bar[144], __ATOMIC_ACQUIRE, __HIP_MEMORY_SCOPE_AGENT) == g)
                    __builtin_amdgcn_s_sleep(2);
            }
        } else {
            while (__hip_atomic_load(&bar[144], __ATOMIC_ACQUIRE, __HIP_MEMORY_SCOPE_AGENT) == g)
                __builtin_amdgcn_s_sleep(2);
        }
        __threadfence();   // device-scope acquire for subsequent reads
    }
    __syncthreads();
}

// ---------------- the persistent kernel: all 128 timesteps, 3 phases/step ----------------
// Plain launch (no cooperative API). Co-residency: 256 blocks, and with
// __launch_bounds__(256,2) + 57.4 KB LDS each CU can host 2 blocks, so the
// 256-CU chip has 2x capacity slack -> all blocks resident before any spins.
__global__ __launch_bounds__(256, 2) void k_persist(
    const float* __restrict__ inp,
    const float* __restrict__ hid, const float* __restrict__ c0,
    const float* __restrict__ mem_bias, const float* __restrict__ r0,
    const ush* __restrict__ B1h, const ush* __restrict__ B1l, const float* __restrict__ bias1,
    const ush* __restrict__ B2h, const ush* __restrict__ B2l, const float* __restrict__ bias2,
    float* __restrict__ h0, float* __restrict__ h1,
    float* __restrict__ rdv, float* __restrict__ o_all,
    float* __restrict__ out, unsigned* __restrict__ bar)
{
    // scratch: phase1/phase2 staging+reduce (aliased in time). 20480 B.
    __shared__ __align__(16) char scratch[20480];
    // persistent per-batch state (block bid owns batch element bid)
    __shared__ float ms[NN * 65];          // memory matrix, pad-65 (bank-conflict-free)
    __shared__ float wr_s[NN], ww_s[NN];   // w states
    // phase3 scratch
    __shared__ float os[OC];
    __shared__ float wgs[NN], wsh[NN];
    __shared__ float red4[4];
    __shared__ float esh[MM], ash[MM];

    const int bid = blockIdx.x;
    const int tid = threadIdx.x;
    const int wid = tid >> 6, l = tid & 63;
    const int rr = l & 15;
    const int kq = (l >> 4) * 8;

    ush (*AH)[32][40] = (ush (*)[32][40])scratch;
    ush (*AL)[32][40] = (ush (*)[32][40])(scratch + 10240);

    // ---- init ----
    for (int i = tid; i < NN * MM; i += 256) {
        int n = i >> 6, m = i & 63;
        ms[n * 65 + m] = mem_bias[i];
    }
    if (tid < NN) { wr_s[tid] = 0.f; ww_s[tid] = 0.f; }
    for (int k = tid; k < CDIM; k += 256) h0[bid * CDIM + k] = hid[bid * CDIM + k];
    if (tid < MM) rdv[bid * MM + tid] = r0[tid];

    // phase1 tile for this block
    const int jt = bid & 31;
    const int m0 = (bid >> 5) * 32;
    // wave-0 epilogue lane-resident state: c cells + bias (4 gates)
    float c_reg[2][4];
    float bjv[4];
    {
        int jg = jt * 16 + rr;
#pragma unroll
        for (int s = 0; s < 2; ++s)
#pragma unroll
            for (int r = 0; r < 4; ++r) c_reg[s][r] = c0[jg];
        bjv[0] = bias1[jg];        bjv[1] = bias1[512 + jg];
        bjv[2] = bias1[1024 + jg]; bjv[3] = bias1[1536 + jg];
    }
    // phase2 tile for this block (valid if bid < 136)
    const int jt2 = bid % 17, mt2 = bid / 17;
    const int mm0 = mt2 * 32;
    const int col2 = jt2 * 16 + (tid & 15);
    float b2v = (col2 < OC) ? bias2[col2] : 0.f;

    gridbar(bar, bid);

    for (int t = 0; t < TT; ++t) {
        const float* hin = (t & 1) ? h1 : h0;
        float* hout      = (t & 1) ? h0 : h1;
        float* out_t = out + (size_t)t * BSZ * ODIM;

        // ================= phase 1: gates GEMM (split-bf16 MFMA) + LSTM =================
        {
            const float* x_t = inp + (size_t)t * BSZ * IDIM;
            f32x4 acc[2][4];
#pragma unroll
            for (int s = 0; s < 2; ++s)
#pragma unroll
                for (int g = 0; g < 4; ++g) acc[s][g] = (f32x4){0.f, 0.f, 0.f, 0.f};

            const int row_s = l >> 1;
            const int cc = (l & 1) * 16;

            for (int i = 0; i < 7; ++i) {
                const int kb = i * 4 + wid;
                const bool act = (kb < NKB1);
                s16x8 bfh[4], bfl[4];
                if (act) {
                    const int boff = ((kb * 32 + jt) * 256 + l) * 8;
#pragma unroll
                    for (int g = 0; g < 4; ++g) {
                        bfh[g] = *(const s16x8*)(B1h + boff + g * 512);
                        bfl[g] = *(const s16x8*)(B1l + boff + g * 512);
                    }
                    const int kg = kb * 32;
                    const float* p;
                    if (kb < 8)       p = x_t + (m0 + row_s) * IDIM + kg + cc;
                    else if (kb < 10) p = rdv + (m0 + row_s) * MM + (kg - IDIM) + cc;
                    else              p = hin + (m0 + row_s) * CDIM + (kg - 320) + cc;
                    float f[16];
                    *(float4*)&f[0]  = ((const float4*)p)[0];
                    *(float4*)&f[4]  = ((const float4*)p)[1];
                    *(float4*)&f[8]  = ((const float4*)p)[2];
                    *(float4*)&f[12] = ((const float4*)p)[3];
                    s16x8 vh0, vl0, vh1, vl1;
#pragma unroll
                    for (int q = 0; q < 8; ++q) {
                        ush h_, l_;
                        split2(f[q], h_, l_);
                        vh0[q] = (short)h_; vl0[q] = (short)l_;
                        split2(f[8 + q], h_, l_);
                        vh1[q] = (short)h_; vl1[q] = (short)l_;
                    }
                    *(s16x8*)&AH[wid][row_s][cc]     = vh0;
                    *(s16x8*)&AH[wid][row_s][cc + 8] = vh1;
                    *(s16x8*)&AL[wid][row_s][cc]     = vl0;
                    *(s16x8*)&AL[wid][row_s][cc + 8] = vl1;
                }
                __syncthreads();
                if (act) {
                    s16x8 a0h = *(const s16x8*)&AH[wid][rr][kq];
                    s16x8 a0l = *(const s16x8*)&AL[wid][rr][kq];
                    s16x8 a1h = *(const s16x8*)&AH[wid][16 + rr][kq];
                    s16x8 a1l = *(const s16x8*)&AL[wid][16 + rr][kq];
#pragma unroll
                    for (int g = 0; g < 4; ++g) {
                        acc[0][g] = MFMA(a0h, bfh[g], acc[0][g], 0, 0, 0);
                        acc[1][g] = MFMA(a1h, bfh[g], acc[1][g], 0, 0, 0);
                        acc[0][g] = MFMA(a0l, bfh[g], acc[0][g], 0, 0, 0);
                        acc[1][g] = MFMA(a1l, bfh[g], acc[1][g], 0, 0, 0);
                        acc[0][g] = MFMA(a0h, bfl[g], acc[0][g], 0, 0, 0);
                        acc[1][g] = MFMA(a1h, bfl[g], acc[1][g], 0, 0, 0);
                    }
                }
                __syncthreads();
            }

            // pairwise split-K reduce: (0+=2), (1+=3), then (0+=1); epilogue on wave 0.
            float* red0 = (float*)scratch;            // [32][4][16] = 8 KB
            float* red1 = (float*)(scratch + 8192);
            if (wid >= 2) {
                float* dst = (wid == 2) ? red0 : red1;
#pragma unroll
                for (int s = 0; s < 2; ++s)
#pragma unroll
                    for (int g = 0; g < 4; ++g)
#pragma unroll
                        for (int r = 0; r < 4; ++r)
                            dst[((s * 16 + (l >> 4) * 4 + r) << 6) + (g << 4) + rr] = acc[s][g][r];
            }
            __syncthreads();
            if (wid < 2) {
                const float* src = (wid == 0) ? red0 : red1;
#pragma unroll
                for (int s = 0; s < 2; ++s)
#pragma unroll
                    for (int g = 0; g < 4; ++g)
#pragma unroll
                        for (int r = 0; r < 4; ++r)
                            acc[s][g][r] += src[((s * 16 + (l >> 4) * 4 + r) << 6) + (g << 4) + rr];
            }
            __syncthreads();
            if (wid == 1) {
#pragma unroll
                for (int s = 0; s < 2; ++s)
#pragma unroll
                    for (int g = 0; g < 4; ++g)
#pragma unroll
                        for (int r = 0; r < 4; ++r)
                            red0[((s * 16 + (l >> 4) * 4 + r) << 6) + (g << 4) + rr] = acc[s][g][r];
            }
            __syncthreads();
            if (wid == 0) {
                const int jg = jt * 16 + rr;
#pragma unroll
                for (int s = 0; s < 2; ++s)
#pragma unroll
                    for (int r = 0; r < 4; ++r) {
                        const int row = s * 16 + (l >> 4) * 4 + r;
                        const int ridx = (row << 6) + rr;
                        float gi = acc[s][0][r] + red0[ridx]        + bjv[0];
                        float gf = acc[s][1][r] + red0[ridx + 16]   + bjv[1];
                        float gg2 = acc[s][2][r] + red0[ridx + 32]  + bjv[2];
                        float go = acc[s][3][r] + red0[ridx + 48]   + bjv[3];
                        float cn = sigmoidf_(gf) * c_reg[s][r] + sigmoidf_(gi) * tanhf(gg2);
                        float hn = sigmoidf_(go) * tanhf(cn);
                        c_reg[s][r] = cn;
                        const int b = m0 + row;
                        hout[b * CDIM + jg] = hn;
                        out_t[b * ODIM + jg] = hn;
                    }
            }
        }

        gridbar(bar, bid);

        // ================= phase 2: heads GEMM (split-bf16 MFMA), 136 blocks =================
        if (bid < 136) {
            f32x4 acc2[2];
            acc2[0] = (f32x4){0.f, 0.f, 0.f, 0.f};
            acc2[1] = (f32x4){0.f, 0.f, 0.f, 0.f};
            const int row_s = l >> 1;
            const int cc = (l & 1) * 16;
            for (int i = 0; i < 4; ++i) {
                const int kb = i * 4 + wid;
                const int boff = ((kb * NJT2 + jt2) * 64 + l) * 8;
                s16x8 bh = *(const s16x8*)(B2h + boff);
                s16x8 bl = *(const s16x8*)(B2l + boff);
                const float* p = hout + (mm0 + row_s) * CDIM + kb * 32 + cc;
                float f[16];
                *(float4*)&f[0]  = ((const float4*)p)[0];
                *(float4*)&f[4]  = ((const float4*)p)[1];
                *(float4*)&f[8]  = ((const float4*)p)[2];
                *(float4*)&f[12] = ((const float4*)p)[3];
                s16x8 vh0, vl0, vh1, vl1;
#pragma unroll
                for (int q = 0; q < 8; ++q) {
                    ush h_, l_;
                    split2(f[q], h_, l_);
                    vh0[q] = (short)h_; vl0[q] = (short)l_;
                    split2(f[8 + q], h_, l_);
                    vh1[q] = (short)h_; vl1[q] = (short)l_;
                }
                *(s16x8*)&AH[wid][row_s][cc]     = vh0;
                *(s16x8*)&AH[wid][row_s][cc + 8] = vh1;
                *(s16x8*)&AL[wid][row_s][cc]     = vl0;
                *(s16x8*)&AL[wid][row_s][cc + 8] = vl1;
                __syncthreads();
                s16x8 a0h = *(const s16x8*)&AH[wid][rr][kq];
                s16x8 a0l = *(const s16x8*)&AL[wid][rr][kq];
                s16x8 a1h = *(const s16x8*)&AH[wid][16 + rr][kq];
                s16x8 a1l = *(const s16x8*)&AL[wid][16 + rr][kq];
                acc2[0] = MFMA(a0h, bh, acc2[0], 0, 0, 0);
                acc2[1] = MFMA(a1h, bh, acc2[1], 0, 0, 0);
                acc2[0] = MFMA(a0l, bh, acc2[0], 0, 0, 0);
                acc2[1] = MFMA(a1l, bh, acc2[1], 0, 0, 0);
                acc2[0] = MFMA(a0h, bl, acc2[0], 0, 0, 0);
                acc2[1] = MFMA(a1h, bl, acc2[1], 0, 0, 0);
                __syncthreads();
            }
            float* red2 = (float*)scratch;  // [4][32][16] = 8 KB
#pragma unroll
            for (int s = 0; s < 2; ++s)
#pragma unroll
                for (int r = 0; r < 4; ++r)
                    red2[((wid * 32 + s * 16 + (l >> 4) * 4 + r) << 4) + rr] = acc2[s][r];
            __syncthreads();
            if (col2 < OC) {
#pragma unroll
                for (int s = 0; s < 2; ++s) {
                    const int row = s * 16 + (tid >> 4);
                    const int j = tid & 15;
                    float o = red2[((row) << 4) + j] + red2[((32 + row) << 4) + j]
                            + red2[((64 + row) << 4) + j] + red2[((96 + row) << 4) + j] + b2v;
                    o_all[(mm0 + row) * OC + col2] = o;
                }
            }
        }

        gridbar(bar, bid);

        // ================= phase 3: addressing + read + memory update (block = batch b) =================
        {
            for (int i = tid; i < OC; i += 256) os[i] = o_all[bid * OC + i];
            __syncthreads();

            for (int head = 0; head < 2; ++head) {
                const int ob = head ? 70 : 0;
                float* wst = head ? ww_s : wr_s;

                float beta = softplusf_(os[ob + 64]);
                float gte  = sigmoidf_(os[ob + 65]);
                float s0r = os[ob + 66], s1r = os[ob + 67], s2r = os[ob + 68];
                float smx = fmaxf(s0r, fmaxf(s1r, s2r));
                float e0 = expf(s0r - smx), e1 = expf(s1r - smx), e2 = expf(s2r - smx);
                float einv = 1.f / (e0 + e1 + e2);
                float s0 = e0 * einv, s1 = e1 * einv, s2 = e2 * einv;
                float gamma = 1.f + softplusf_(os[ob + 69]);

                float simv = -1e30f;
                if (tid < NN) {
                    float dot = 0.f, nm2 = 0.f, nk2 = 0.f;
                    const float* mrow = ms + tid * 65;
#pragma unroll 8
                    for (int m = 0; m < MM; ++m) {
                        float mv = mrow[m] + 1e-16f;
                        float kv = os[ob + m] + 1e-16f;
                        dot += mv * kv; nm2 += mv * mv; nk2 += kv * kv;
                    }
                    float nm = fmaxf(sqrtf(nm2), 1e-8f);
                    float nk = fmaxf(sqrtf(nk2), 1e-8f);
                    simv = beta * dot / (nm * nk);
                }
                float v = simv;
#pragma unroll
                for (int off = 32; off; off >>= 1) v = fmaxf(v, __shfl_xor(v, off));
                if ((tid & 63) == 0) red4[tid >> 6] = v;
                __syncthreads();
                float smax = fmaxf(fmaxf(red4[0], red4[1]), fmaxf(red4[2], red4[3]));
                __syncthreads();

                float pv = (tid < NN) ? expf(simv - smax) : 0.f;
                v = pv;
#pragma unroll
                for (int off = 32; off; off >>= 1) v += __shfl_xor(v, off);
                if ((tid & 63) == 0) red4[tid >> 6] = v;
                __syncthreads();
                float psum = red4[0] + red4[1] + red4[2] + red4[3];
                __syncthreads();

                if (tid < NN) {
                    float wc = pv / psum;
                    wgs[tid] = gte * wc + (1.f - gte) * wst[tid];
                }
                __syncthreads();

                float wv_ = 0.f;
                if (tid < NN) {
                    int nl = (tid + NN - 1) & (NN - 1), nr = (tid + 1) & (NN - 1);
                    float wwv = s0 * wgs[nl] + s1 * wgs[tid] + s2 * wgs[nr];
                    wv_ = powf(wwv, gamma);
                }
                v = wv_;
#pragma unroll
                for (int off = 32; off; off >>= 1) v += __shfl_xor(v, off);
                if ((tid & 63) == 0) red4[tid >> 6] = v;
                __syncthreads();
                float wsum = red4[0] + red4[1] + red4[2] + red4[3];
                __syncthreads();

                if (tid < NN) {
                    float wfin = wv_ / (wsum + 1e-16f);
                    wsh[tid] = wfin;
                    wst[tid] = wfin;
                }
                __syncthreads();

                if (head == 0) {
                    if (tid < MM) {
                        float r = 0.f;
#pragma unroll 8
                        for (int n = 0; n < NN; ++n) r += wsh[n] * ms[n * 65 + tid];
                        rdv[bid * MM + tid] = r;
                        out_t[bid * ODIM + CDIM + tid] = r;
                    }
                    __syncthreads();
                } else {
                    if (tid < MM) {
                        esh[tid] = sigmoidf_(os[140 + tid]);
                        ash[tid] = os[204 + tid];
                    }
                    __syncthreads();
                    for (int i = tid; i < NN * MM / 4; i += 256) {
                        int n = i >> 4, m4 = (i & 15) * 4;
                        float wvn = wsh[n];
#pragma unroll
                        for (int q = 0; q < 4; ++q) {
                            float mv = ms[n * 65 + m4 + q];
                            ms[n * 65 + m4 + q] = mv * (1.f - wvn * esh[m4 + q]) + wvn * ash[m4 + q];
                        }
                    }
                    __syncthreads();
                }
            }
        }

        gridbar(bar, bid);
    }
}

extern "C" void kernel_launch(void* const* d_in, const int* in_sizes, int n_in,
                              void* d_out, int out_size, void* d_ws, size_t ws_size,
                              hipStream_t stream) {
    const float* inp      = (const float*)d_in[0];
    const float* hid      = (const float*)d_in[1];
    const float* c0       = (const float*)d_in[2];
    const float* mem_bias = (const float*)d_in[3];
    const float* r0       = (const float*)d_in[4];
    const float* W_ih     = (const float*)d_in[5];
    const float* W_hh     = (const float*)d_in[6];
    const float* b_ih     = (const float*)d_in[7];
    const float* b_hh     = (const float*)d_in[8];
    const float* read_W   = (const float*)d_in[9];
    const float* read_b   = (const float*)d_in[10];
    const float* write_W  = (const float*)d_in[11];
    const float* write_b  = (const float*)d_in[12];
    float* out = (float*)d_out;

    char* p = (char*)d_ws;
    auto alloc = [&](size_t bytes) { char* r = p; p += (bytes + 255) & ~(size_t)255; return r; };
    const size_t nB1 = (size_t)NKB1 * NJT1 * 4 * 64 * 8;
    const size_t nB2 = (size_t)NKB2 * NJT2 * 64 * 8;
    ush* B1h = (ush*)alloc(nB1 * 2);
    ush* B1l = (ush*)alloc(nB1 * 2);
    ush* B2h = (ush*)alloc(nB2 * 2);
    ush* B2l = (ush*)alloc(nB2 * 2);
    float* bias1 = (float*)alloc(GJ * 4);
    float* bias2 = (float*)alloc(NJT2 * 16 * 4);
    float* h0    = (float*)alloc((size_t)BSZ * CDIM * 4);
    float* h1    = (float*)alloc((size_t)BSZ * CDIM * 4);
    float* rdv   = (float*)alloc((size_t)BSZ * MM * 4);
    float* o_all = (float*)alloc((size_t)BSZ * OC * 4);
    unsigned* bar = (unsigned*)alloc(256 * 4);

    k_packB1<<<2048, 256, 0, stream>>>(W_ih, W_hh, b_ih, b_hh, B1h, B1l, bias1);
    k_packB2<<<544, 256, 0, stream>>>(read_W, read_b, write_W, write_b, B2h, B2l, bias2);
    k_barinit<<<1, 64, 0, stream>>>(bar);

    k_persist<<<dim3(NBLK), dim3(256), 0, stream>>>(
        inp, hid, c0, mem_bias, r0,
        B1h, B1l, bias1, B2h, B2l, bias2,
        h0, h1, rdv, o_all, out, bar);
}

// Round 5
// 6103.516 us; speedup vs baseline: 2.3135x; 2.3135x over previous
//
#include <hip/hip_runtime.h>
#include <math.h>

#define TT   128
#define BSZ  256
#define IDIM 256
#define CDIM 512
#define NN   128
#define MM   64
#define KTOT 832
#define GJ   2048
#define ODIM 576
#define OC   268

#define NKB1 26            // K-blocks of 32 for gates GEMM (832/32)
#define NJT1 32            // j-tiles of 16 across 512
#define NBLK 256

typedef __attribute__((ext_vector_type(8))) short s16x8;
typedef __attribute__((ext_vector_type(4))) float f32x4;
typedef unsigned short ush;
#define MFMA __builtin_amdgcn_mfma_f32_16x16x32_bf16

__device__ __forceinline__ float sigmoidf_(float x) { return 1.0f / (1.0f + expf(-x)); }
__device__ __forceinline__ float softplusf_(float x) {
    return (x > 0.f) ? (x + log1pf(expf(-x))) : log1pf(expf(x));
}
__device__ __forceinline__ ush f2bf(float f) {
    unsigned int u = __builtin_bit_cast(unsigned int, f);
    u += 0x7FFFu + ((u >> 16) & 1u);
    return (ush)(u >> 16);
}
__device__ __forceinline__ float bf2f(ush b) {
    unsigned int u = ((unsigned int)b) << 16;
    return __builtin_bit_cast(float, u);
}
__device__ __forceinline__ void split2(float v, ush& h, ush& lo) {
    h = f2bf(v);
    lo = f2bf(v - bf2f(h));
}

// ---- IC-coherent (cross-XCD) accesses: bypass L1/L2 with sc0 sc1 ----
__device__ __forceinline__ void load16_sc(const float* p, float4& a, float4& b, float4& c, float4& d) {
    asm volatile(
        "global_load_dwordx4 %0, %4, off sc0 sc1\n\t"
        "global_load_dwordx4 %1, %4, off offset:16 sc0 sc1\n\t"
        "global_load_dwordx4 %2, %4, off offset:32 sc0 sc1\n\t"
        "global_load_dwordx4 %3, %4, off offset:48 sc0 sc1\n\t"
        "s_waitcnt vmcnt(0)"
        : "=&v"(a), "=&v"(b), "=&v"(c), "=&v"(d)
        : "v"(p)
        : "memory");
}
__device__ __forceinline__ void load4_sc(const float* p, float4& a) {
    asm volatile(
        "global_load_dwordx4 %0, %1, off sc0 sc1\n\t"
        "s_waitcnt vmcnt(0)"
        : "=&v"(a) : "v"(p) : "memory");
}
__device__ __forceinline__ void store_sc(float* p, float v) {
    asm volatile("global_store_dword %0, %1, off sc0 sc1" :: "v"(p), "v"(v) : "memory");
}

// ---------------- prep: pack gates weights into MFMA fragment order, split hi/lo ----------------
__global__ void k_packB1(const float* __restrict__ W_ih, const float* __restrict__ W_hh,
                         const float* __restrict__ b_ih, const float* __restrict__ b_hh,
                         ush* __restrict__ Bh, ush* __restrict__ Bl, float* __restrict__ bias)
{
    const int total = NKB1 * NJT1 * 4 * 64 * 8;
    for (int idx = blockIdx.x * 256 + threadIdx.x; idx < total + GJ; idx += gridDim.x * 256) {
        if (idx < total) {
            int e  = idx & 7;
            int l  = (idx >> 3) & 63;
            int g  = (idx >> 9) & 3;
            int jt = (idx >> 11) & 31;
            int kb = idx >> 16;
            int k  = kb * 32 + ((l >> 4) << 3) + e;
            int n  = g * 512 + jt * 16 + (l & 15);
            float v = (k < 320) ? W_ih[n * 320 + k] : W_hh[n * 512 + (k - 320)];
            ush h_, l_;
            split2(v, h_, l_);
            Bh[idx] = h_; Bl[idx] = l_;
        } else {
            int j = idx - total;
            bias[j] = b_ih[j] + b_hh[j];
        }
    }
}

// ---------------- prep: pack head weights col-major fp32 W2T[j][k] ----------------
__global__ void k_packW2(const float* __restrict__ rW, const float* __restrict__ rb,
                         const float* __restrict__ wW, const float* __restrict__ wb,
                         float* __restrict__ W2T, float* __restrict__ bias2)
{
    const int total = 272 * 512;
    for (int idx = blockIdx.x * 256 + threadIdx.x; idx < total + 272; idx += gridDim.x * 256) {
        if (idx < total) {
            int j = idx >> 9, k = idx & 511;
            float v = 0.f;
            if (j < 70)      v = rW[k * 70 + j];
            else if (j < OC) v = wW[k * 198 + (j - 70)];
            W2T[idx] = v;
        } else {
            int j = idx - total;
            bias2[j] = (j < 70) ? rb[j] : ((j < OC) ? wb[j - 70] : 0.f);
        }
    }
}

// ---------------- barrier state init (re-run every launch; monotonic counters) ----------------
__global__ void k_barinit(unsigned* __restrict__ bar) {
    for (int i = threadIdx.x; i < 160; i += 64) bar[i] = 0u;
}

// Fence-free two-level grid barrier. Monotonic counters, RELAXED agent atomics only.
// Safe because: all cross-block data moves via sc0/sc1 (IC) accesses, each wave's
// stores are vmcnt-drained before block arrival (__syncthreads drains vmcnt), and
// response-ordering of IC atomics gives transitive visibility.
__device__ __forceinline__ void gridbar(unsigned* bar, int bid) {
    asm volatile("s_waitcnt vmcnt(0)" ::: "memory");
    __syncthreads();
    if (threadIdx.x == 0) {
        unsigned g = __hip_atomic_load(&bar[144], __ATOMIC_RELAXED, __HIP_MEMORY_SCOPE_AGENT);
        int grp = bid >> 5;
        unsigned old = __hip_atomic_fetch_add(&bar[grp * 16], 1u, __ATOMIC_RELAXED, __HIP_MEMORY_SCOPE_AGENT);
        if (old == g * 32u + 31u) {
            unsigned r = __hip_atomic_fetch_add(&bar[128], 1u, __ATOMIC_RELAXED, __HIP_MEMORY_SCOPE_AGENT);
            if (r == g * 8u + 7u) {
                __hip_atomic_store(&bar[144], g + 1u, __ATOMIC_RELAXED, __HIP_MEMORY_SCOPE_AGENT);
            } else {
                while (__hip_atomic_load(&bar[144], __ATOMIC_RELAXED, __HIP_MEMORY_SCOPE_AGENT) == g) {}
            }
        } else {
            while (__hip_atomic_load(&bar[144], __ATOMIC_RELAXED, __HIP_MEMORY_SCOPE_AGENT) == g) {}
        }
    }
    __syncthreads();
}

// ---------------- persistent kernel: 128 timesteps, 2 phases/step ----------------
__global__ __launch_bounds__(256, 2) void k_persist(
    const float* __restrict__ inp,
    const float* __restrict__ hid, const float* __restrict__ c0,
    const float* __restrict__ mem_bias, const float* __restrict__ r0,
    const ush* __restrict__ B1h, const ush* __restrict__ B1l, const float* __restrict__ bias1,
    const float* __restrict__ W2T, const float* __restrict__ bias2,
    float* __restrict__ h0, float* __restrict__ h1,
    float* __restrict__ rdv,
    float* __restrict__ out, unsigned* __restrict__ bar)
{
    // scratch: P1 staging/reduce, then P23 hs/os/esh/ash (aliased in time). 20480 B.
    __shared__ __align__(16) char scratch[20480];
    // persistent per-batch state (block bid owns batch element bid)
    __shared__ float ms[NN * 65];          // memory matrix, pad-65
    __shared__ float wr_s[NN], ww_s[NN];   // w states
    __shared__ float wgs[NN], wsh[NN];
    __shared__ float red4[4];

    const int bid = blockIdx.x;
    const int tid = threadIdx.x;
    const int wid = tid >> 6, l = tid & 63;
    const int rr = l & 15;
    const int kq = (l >> 4) * 8;

    ush (*AH)[32][40] = (ush (*)[32][40])scratch;
    ush (*AL)[32][40] = (ush (*)[32][40])(scratch + 10240);

    // ---- init ----
    for (int i = tid; i < NN * MM; i += 256) {
        int n = i >> 6, m = i & 63;
        ms[n * 65 + m] = mem_bias[i];
    }
    if (tid < NN) { wr_s[tid] = 0.f; ww_s[tid] = 0.f; }
    for (int k = tid; k < CDIM; k += 256) store_sc(&h0[bid * CDIM + k], hid[bid * CDIM + k]);
    if (tid < MM) store_sc(&rdv[bid * MM + tid], r0[tid]);

    // phase1 tile for this block
    const int jt = bid & 31;
    const int m0 = (bid >> 5) * 32;
    float c_reg[2][4];
    float bjv[4];
    {
        int jg = jt * 16 + rr;
#pragma unroll
        for (int s = 0; s < 2; ++s)
#pragma unroll
            for (int r = 0; r < 4; ++r) c_reg[s][r] = c0[jg];
        bjv[0] = bias1[jg];        bjv[1] = bias1[512 + jg];
        bjv[2] = bias1[1024 + jg]; bjv[3] = bias1[1536 + jg];
    }

    gridbar(bar, bid);

    for (int t = 0; t < TT; ++t) {
        const float* hin = (t & 1) ? h1 : h0;
        float* hout      = (t & 1) ? h0 : h1;
        float* out_t = out + (size_t)t * BSZ * ODIM;

        // ================= phase 1: gates GEMM (split-bf16 MFMA) + LSTM =================
        {
            const float* x_t = inp + (size_t)t * BSZ * IDIM;
            f32x4 acc[2][4];
#pragma unroll
            for (int s = 0; s < 2; ++s)
#pragma unroll
                for (int g = 0; g < 4; ++g) acc[s][g] = (f32x4){0.f, 0.f, 0.f, 0.f};

            const int row_s = l >> 1;
            const int cc = (l & 1) * 16;

            for (int i = 0; i < 7; ++i) {
                const int kb = i * 4 + wid;
                const bool act = (kb < NKB1);
                s16x8 bfh[4], bfl[4];
                if (act) {
                    const int boff = ((kb * 32 + jt) * 256 + l) * 8;
#pragma unroll
                    for (int g = 0; g < 4; ++g) {
                        bfh[g] = *(const s16x8*)(B1h + boff + g * 512);
                        bfl[g] = *(const s16x8*)(B1l + boff + g * 512);
                    }
                    const int kg = kb * 32;
                    float f[16];
                    if (kb < 8) {
                        const float* p = x_t + (m0 + row_s) * IDIM + kg + cc;
                        *(float4*)&f[0]  = ((const float4*)p)[0];
                        *(float4*)&f[4]  = ((const float4*)p)[1];
                        *(float4*)&f[8]  = ((const float4*)p)[2];
                        *(float4*)&f[12] = ((const float4*)p)[3];
                    } else {
                        const float* p = (kb < 10)
                            ? rdv + (m0 + row_s) * MM + (kg - IDIM) + cc
                            : hin + (m0 + row_s) * CDIM + (kg - 320) + cc;
                        load16_sc(p, *(float4*)&f[0], *(float4*)&f[4], *(float4*)&f[8], *(float4*)&f[12]);
                    }
                    s16x8 vh0, vl0, vh1, vl1;
#pragma unroll
                    for (int q = 0; q < 8; ++q) {
                        ush h_, l_;
                        split2(f[q], h_, l_);
                        vh0[q] = (short)h_; vl0[q] = (short)l_;
                        split2(f[8 + q], h_, l_);
                        vh1[q] = (short)h_; vl1[q] = (short)l_;
                    }
                    *(s16x8*)&AH[wid][row_s][cc]     = vh0;
                    *(s16x8*)&AH[wid][row_s][cc + 8] = vh1;
                    *(s16x8*)&AL[wid][row_s][cc]     = vl0;
                    *(s16x8*)&AL[wid][row_s][cc + 8] = vl1;
                }
                __syncthreads();
                if (act) {
                    s16x8 a0h = *(const s16x8*)&AH[wid][rr][kq];
                    s16x8 a0l = *(const s16x8*)&AL[wid][rr][kq];
                    s16x8 a1h = *(const s16x8*)&AH[wid][16 + rr][kq];
                    s16x8 a1l = *(const s16x8*)&AL[wid][16 + rr][kq];
#pragma unroll
                    for (int g = 0; g < 4; ++g) {
                        acc[0][g] = MFMA(a0h, bfh[g], acc[0][g], 0, 0, 0);
                        acc[1][g] = MFMA(a1h, bfh[g], acc[1][g], 0, 0, 0);
                        acc[0][g] = MFMA(a0l, bfh[g], acc[0][g], 0, 0, 0);
                        acc[1][g] = MFMA(a1l, bfh[g], acc[1][g], 0, 0, 0);
                        acc[0][g] = MFMA(a0h, bfl[g], acc[0][g], 0, 0, 0);
                        acc[1][g] = MFMA(a1h, bfl[g], acc[1][g], 0, 0, 0);
                    }
                }
                __syncthreads();
            }

            // pairwise split-K reduce, epilogue on wave 0
            float* red0 = (float*)scratch;
            float* red1 = (float*)(scratch + 8192);
            if (wid >= 2) {
                float* dst = (wid == 2) ? red0 : red1;
#pragma unroll
                for (int s = 0; s < 2; ++s)
#pragma unroll
                    for (int g = 0; g < 4; ++g)
#pragma unroll
                        for (int r = 0; r < 4; ++r)
                            dst[((s * 16 + (l >> 4) * 4 + r) << 6) + (g << 4) + rr] = acc[s][g][r];
            }
            __syncthreads();
            if (wid < 2) {
                const float* src = (wid == 0) ? red0 : red1;
#pragma unroll
                for (int s = 0; s < 2; ++s)
#pragma unroll
                    for (int g = 0; g < 4; ++g)
#pragma unroll
                        for (int r = 0; r < 4; ++r)
                            acc[s][g][r] += src[((s * 16 + (l >> 4) * 4 + r) << 6) + (g << 4) + rr];
            }
            __syncthreads();
            if (wid == 1) {
#pragma unroll
                for (int s = 0; s < 2; ++s)
#pragma unroll
                    for (int g = 0; g < 4; ++g)
#pragma unroll
                        for (int r = 0; r < 4; ++r)
                            red0[((s * 16 + (l >> 4) * 4 + r) << 6) + (g << 4) + rr] = acc[s][g][r];
            }
            __syncthreads();
            if (wid == 0) {
                const int jg = jt * 16 + rr;
#pragma unroll
                for (int s = 0; s < 2; ++s)
#pragma unroll
                    for (int r = 0; r < 4; ++r) {
                        const int row = s * 16 + (l >> 4) * 4 + r;
                        const int ridx = (row << 6) + rr;
                        float gi  = acc[s][0][r] + red0[ridx]       + bjv[0];
                        float gf  = acc[s][1][r] + red0[ridx + 16]  + bjv[1];
                        float gg2 = acc[s][2][r] + red0[ridx + 32]  + bjv[2];
                        float go  = acc[s][3][r] + red0[ridx + 48]  + bjv[3];
                        float cn = sigmoidf_(gf) * c_reg[s][r] + sigmoidf_(gi) * tanhf(gg2);
                        float hn = sigmoidf_(go) * tanhf(cn);
                        c_reg[s][r] = cn;
                        const int b = m0 + row;
                        store_sc(&hout[b * CDIM + jg], hn);
                        out_t[b * ODIM + jg] = hn;
                    }
            }
        }

        gridbar(bar, bid);

        // ========== phase 2+3 fused: heads GEMM (VALU) + addressing + memory update ==========
        {
            float* hs  = (float*)scratch;            // 512 floats
            float* os  = (float*)(scratch + 2048);   // 272 floats
            float* esh = (float*)(scratch + 3200);   // 64
            float* ash = (float*)(scratch + 3456);   // 64

            if (tid < 128) {
                float4 hv;
                load4_sc(hout + bid * CDIM + tid * 4, hv);
                *(float4*)&hs[tid * 4] = hv;
            }
            __syncthreads();

            // heads GEMM: o[j] = bias2[j] + sum_k hs[k] * W2T[j][k]
            for (int j = tid; j < 272; j += 256) {
                float accv = bias2[j];
                const float* wrow = W2T + j * 512;
#pragma unroll 4
                for (int k = 0; k < 512; k += 4) {
                    float4 wv = *(const float4*)&wrow[k];
                    accv += hs[k] * wv.x + hs[k + 1] * wv.y + hs[k + 2] * wv.z + hs[k + 3] * wv.w;
                }
                os[j] = accv;
            }
            __syncthreads();

            for (int head = 0; head < 2; ++head) {
                const int ob = head ? 70 : 0;
                float* wst = head ? ww_s : wr_s;

                float beta = softplusf_(os[ob + 64]);
                float gte  = sigmoidf_(os[ob + 65]);
                float s0r = os[ob + 66], s1r = os[ob + 67], s2r = os[ob + 68];
                float smx = fmaxf(s0r, fmaxf(s1r, s2r));
                float e0 = expf(s0r - smx), e1 = expf(s1r - smx), e2 = expf(s2r - smx);
                float einv = 1.f / (e0 + e1 + e2);
                float s0 = e0 * einv, s1 = e1 * einv, s2 = e2 * einv;
                float gamma = 1.f + softplusf_(os[ob + 69]);

                float simv = -1e30f;
                if (tid < NN) {
                    float dot = 0.f, nm2 = 0.f, nk2 = 0.f;
                    const float* mrow = ms + tid * 65;
#pragma unroll 8
                    for (int m = 0; m < MM; ++m) {
                        float mv = mrow[m] + 1e-16f;
                        float kv = os[ob + m] + 1e-16f;
                        dot += mv * kv; nm2 += mv * mv; nk2 += kv * kv;
                    }
                    float nm = fmaxf(sqrtf(nm2), 1e-8f);
                    float nk = fmaxf(sqrtf(nk2), 1e-8f);
                    simv = beta * dot / (nm * nk);
                }
                float v = simv;
#pragma unroll
                for (int off = 32; off; off >>= 1) v = fmaxf(v, __shfl_xor(v, off));
                if ((tid & 63) == 0) red4[tid >> 6] = v;
                __syncthreads();
                float smax = fmaxf(fmaxf(red4[0], red4[1]), fmaxf(red4[2], red4[3]));
                __syncthreads();

                float pv = (tid < NN) ? expf(simv - smax) : 0.f;
                v = pv;
#pragma unroll
                for (int off = 32; off; off >>= 1) v += __shfl_xor(v, off);
                if ((tid & 63) == 0) red4[tid >> 6] = v;
                __syncthreads();
                float psum = red4[0] + red4[1] + red4[2] + red4[3];
                __syncthreads();

                if (tid < NN) {
                    float wc = pv / psum;
                    wgs[tid] = gte * wc + (1.f - gte) * wst[tid];
                }
                __syncthreads();

                float wv_ = 0.f;
                if (tid < NN) {
                    int nl = (tid + NN - 1) & (NN - 1), nr = (tid + 1) & (NN - 1);
                    float wwv = s0 * wgs[nl] + s1 * wgs[tid] + s2 * wgs[nr];
                    wv_ = powf(wwv, gamma);
                }
                v = wv_;
#pragma unroll
                for (int off = 32; off; off >>= 1) v += __shfl_xor(v, off);
                if ((tid & 63) == 0) red4[tid >> 6] = v;
                __syncthreads();
                float wsum = red4[0] + red4[1] + red4[2] + red4[3];
                __syncthreads();

                if (tid < NN) {
                    float wfin = wv_ / (wsum + 1e-16f);
                    wsh[tid] = wfin;
                    wst[tid] = wfin;
                }
                __syncthreads();

                if (head == 0) {
                    if (tid < MM) {
                        float r = 0.f;
#pragma unroll 8
                        for (int n = 0; n < NN; ++n) r += wsh[n] * ms[n * 65 + tid];
                        store_sc(&rdv[bid * MM + tid], r);
                        out_t[bid * ODIM + CDIM + tid] = r;
                    }
                    __syncthreads();
                } else {
                    if (tid < MM) {
                        esh[tid] = sigmoidf_(os[140 + tid]);
                        ash[tid] = os[204 + tid];
                    }
                    __syncthreads();
                    for (int i = tid; i < NN * MM / 4; i += 256) {
                        int n = i >> 4, m4 = (i & 15) * 4;
                        float wvn = wsh[n];
#pragma unroll
                        for (int q = 0; q < 4; ++q) {
                            float mv = ms[n * 65 + m4 + q];
                            ms[n * 65 + m4 + q] = mv * (1.f - wvn * esh[m4 + q]) + wvn * ash[m4 + q];
                        }
                    }
                    __syncthreads();
                }
            }
        }

        gridbar(bar, bid);
    }
}

extern "C" void kernel_launch(void* const* d_in, const int* in_sizes, int n_in,
                              void* d_out, int out_size, void* d_ws, size_t ws_size,
                              hipStream_t stream) {
    const float* inp      = (const float*)d_in[0];
    const float* hid      = (const float*)d_in[1];
    const float* c0       = (const float*)d_in[2];
    const float* mem_bias = (const float*)d_in[3];
    const float* r0       = (const float*)d_in[4];
    const float* W_ih     = (const float*)d_in[5];
    const float* W_hh     = (const float*)d_in[6];
    const float* b_ih     = (const float*)d_in[7];
    const float* b_hh     = (const float*)d_in[8];
    const float* read_W   = (const float*)d_in[9];
    const float* read_b   = (const float*)d_in[10];
    const float* write_W  = (const float*)d_in[11];
    const float* write_b  = (const float*)d_in[12];
    float* out = (float*)d_out;

    char* p = (char*)d_ws;
    auto alloc = [&](size_t bytes) { char* r = p; p += (bytes + 255) & ~(size_t)255; return r; };
    const size_t nB1 = (size_t)NKB1 * NJT1 * 4 * 64 * 8;
    ush* B1h = (ush*)alloc(nB1 * 2);
    ush* B1l = (ush*)alloc(nB1 * 2);
    float* bias1 = (float*)alloc(GJ * 4);
    float* W2T   = (float*)alloc(272 * 512 * 4);
    float* bias2 = (float*)alloc(272 * 4);
    float* h0    = (float*)alloc((size_t)BSZ * CDIM * 4);
    float* h1    = (float*)alloc((size_t)BSZ * CDIM * 4);
    float* rdv   = (float*)alloc((size_t)BSZ * MM * 4);
    unsigned* bar = (unsigned*)alloc(256 * 4);

    k_packB1<<<2048, 256, 0, stream>>>(W_ih, W_hh, b_ih, b_hh, B1h, B1l, bias1);
    k_packW2<<<546, 256, 0, stream>>>(read_W, read_b, write_W, write_b, W2T, bias2);
    k_barinit<<<1, 64, 0, stream>>>(bar);

    k_persist<<<dim3(NBLK), dim3(256), 0, stream>>>(
        inp, hid, c0, mem_bias, r0,
        B1h, B1l, bias1, W2T, bias2,
        h0, h1, rdv, out, bar);
}

// Round 7
// 4946.375 us; speedup vs baseline: 2.8547x; 1.2339x over previous
//
#include <hip/hip_runtime.h>
#include <math.h>

#define TT   128
#define BSZ  256
#define IDIM 256
#define CDIM 512
#define NN   128
#define MM   64
#define GJ   2048
#define ODIM 576
#define OC   268
#define NKB1 26
#define NBLK 256

typedef __attribute__((ext_vector_type(8))) short s16x8;
typedef __attribute__((ext_vector_type(4))) float f32x4;
typedef unsigned short ush;
#define MFMA __builtin_amdgcn_mfma_f32_16x16x32_bf16

__device__ __forceinline__ float sigmoidf_(float x) { return 1.0f / (1.0f + expf(-x)); }
__device__ __forceinline__ float softplusf_(float x) {
    return (x > 0.f) ? (x + log1pf(expf(-x))) : log1pf(expf(x));
}
__device__ __forceinline__ ush f2bf(float f) {
    unsigned int u = __builtin_bit_cast(unsigned int, f);
    u += 0x7FFFu + ((u >> 16) & 1u);
    return (ush)(u >> 16);
}
__device__ __forceinline__ float bf2f(ush b) {
    unsigned int u = ((unsigned int)b) << 16;
    return __builtin_bit_cast(float, u);
}
__device__ __forceinline__ void split2(float v, ush& h, ush& lo) {
    h = f2bf(v);
    lo = f2bf(v - bf2f(h));
}

// ---- IC-coherent accesses (cross-XCD), split issue/drain ----
__device__ __forceinline__ void load4_sc_async(const float* p, f32x4& a) {
    asm volatile("global_load_dwordx4 %0, %1, off sc0 sc1" : "=&v"(a) : "v"(p));
}
__device__ __forceinline__ void load16_sc_async(const float* p, f32x4& a, f32x4& b, f32x4& c, f32x4& d) {
    asm volatile(
        "global_load_dwordx4 %0, %4, off sc0 sc1\n\t"
        "global_load_dwordx4 %1, %4, off offset:16 sc0 sc1\n\t"
        "global_load_dwordx4 %2, %4, off offset:32 sc0 sc1\n\t"
        "global_load_dwordx4 %3, %4, off offset:48 sc0 sc1"
        : "=&v"(a), "=&v"(b), "=&v"(c), "=&v"(d) : "v"(p));
}
__device__ __forceinline__ void store1_sc(float* p, float v) {
    asm volatile("global_store_dword %0, %1, off sc0 sc1" :: "v"(p), "v"(v) : "memory");
}
__device__ __forceinline__ void store4_sc(float* p, f32x4 v) {
    asm volatile("global_store_dwordx4 %0, %1, off sc0 sc1" :: "v"(p), "v"(v) : "memory");
}
// drain all outstanding VMEM; sched_barrier stops hoisting of consumers (rule #18)
#define DRAIN() do { asm volatile("s_waitcnt vmcnt(0)" ::: "memory"); __builtin_amdgcn_sched_barrier(0); } while (0)

__device__ __forceinline__ void spin_ge(unsigned* p, unsigned tgt) {
    while (__hip_atomic_load(p, __ATOMIC_RELAXED, __HIP_MEMORY_SCOPE_AGENT) < tgt)
        __builtin_amdgcn_s_sleep(2);
    __builtin_amdgcn_sched_barrier(0);
}
__device__ __forceinline__ void inc_cnt(unsigned* p) {
    __hip_atomic_fetch_add(p, 1u, __ATOMIC_RELAXED, __HIP_MEMORY_SCOPE_AGENT);
}

// ---------------- prep: pack gates weights (MFMA fragment order, split hi/lo) ----------------
__global__ void k_packB1(const float* __restrict__ W_ih, const float* __restrict__ W_hh,
                         const float* __restrict__ b_ih, const float* __restrict__ b_hh,
                         ush* __restrict__ Bh, ush* __restrict__ Bl, float* __restrict__ bias)
{
    const int total = NKB1 * 32 * 4 * 64 * 8;
    for (int idx = blockIdx.x * 256 + threadIdx.x; idx < total + GJ; idx += gridDim.x * 256) {
        if (idx < total) {
            int e  = idx & 7;
            int l  = (idx >> 3) & 63;
            int g  = (idx >> 9) & 3;
            int jt = (idx >> 11) & 31;
            int kb = idx >> 16;
            int k  = kb * 32 + ((l >> 4) << 3) + e;
            int n  = g * 512 + jt * 16 + (l & 15);
            float v = (k < 320) ? W_ih[n * 320 + k] : W_hh[n * 512 + (k - 320)];
            ush h_, l_;
            split2(v, h_, l_);
            Bh[idx] = h_; Bl[idx] = l_;
        } else {
            int j = idx - total;
            bias[j] = b_ih[j] + b_hh[j];
        }
    }
}

// ---------------- prep: pack head weights W2P[jt][col][16] (j-sliced for A partials) ----------------
__global__ void k_packW2P(const float* __restrict__ rW, const float* __restrict__ rb,
                          const float* __restrict__ wW, const float* __restrict__ wb,
                          float* __restrict__ W2P, float* __restrict__ bias2)
{
    const int total = 32 * 272 * 16;
    for (int idx = blockIdx.x * 256 + threadIdx.x; idx < total + 272; idx += gridDim.x * 256) {
        if (idx < total) {
            int jj  = idx & 15;
            int q   = idx >> 4;
            int col = q % 272;
            int jt  = q / 272;
            int k   = jt * 16 + jj;
            float v = 0.f;
            if (col < 70)      v = rW[k * 70 + col];
            else if (col < OC) v = wW[k * 198 + (col - 70)];
            W2P[idx] = v;
        } else {
            int col = idx - total;
            bias2[col] = (col < 70) ? rb[col] : ((col < OC) ? wb[col - 70] : 0.f);
        }
    }
}

__global__ void k_barinit(unsigned* __restrict__ bar) {
    for (int i = threadIdx.x; i < 1024; i += 64) bar[i] = 0u;
}

// ---------------- persistent dataflow kernel ----------------
__global__ __launch_bounds__(256, 1) void k_persist(
    const float* __restrict__ inp,
    const float* __restrict__ hid, const float* __restrict__ c0,
    const float* __restrict__ mem_bias, const float* __restrict__ r0,
    const ush* __restrict__ B1h, const ush* __restrict__ B1l, const float* __restrict__ bias1,
    const float* __restrict__ W2P, const float* __restrict__ bias2,
    float* __restrict__ h0, float* __restrict__ h1,
    float* __restrict__ rdv, float* __restrict__ opart,
    float* __restrict__ out, unsigned* __restrict__ bar)
{
    __shared__ __align__(16) char scratch[20480];   // stage AH|AL; aliases red0/red1/hsl
    __shared__ float ms[NN * 65];
    __shared__ float os_l[272];
    __shared__ float wr_s[NN], ww_s[NN], wgs[NN], wsh[NN];
    __shared__ float red4[4];
    __shared__ float esh[MM], ash[MM];

    ush (*AH)[32][40] = (ush (*)[32][40])scratch;
    ush (*AL)[32][40] = (ush (*)[32][40])(scratch + 10240);
    float* red0 = (float*)scratch;
    float* red1 = (float*)(scratch + 8192);
    float* hsl  = (float*)(scratch + 16384);        // [32][16]

    const int bid = blockIdx.x;
    const int tid = threadIdx.x;
    const int wid = tid >> 6, l = tid & 63;
    const int rr = l & 15;
    const int kq = (l >> 4) * 8;
    const int row_s = l >> 1;
    const int cc = (l & 1) * 16;

    const int grp = bid >> 5;          // m-group (batch rows grp*32..+31)
    const int jt  = bid & 31;          // j-tile
    const int m0  = grp * 32;
    const int b   = bid;               // owned batch element

    unsigned* cntA = bar + grp * 32;         // "A inputs ready" (init + B incs)
    unsigned* cntB = bar + 512 + grp * 32;   // "h+opart ready"  (A incs)
    const size_t OPN = (size_t)BSZ * 32 * 272;

    // ---- init ----
    for (int i = tid; i < NN * MM; i += 256) {
        int n = i >> 6, m = i & 63;
        ms[n * 65 + m] = mem_bias[i];
    }
    if (tid < NN) { wr_s[tid] = 0.f; ww_s[tid] = 0.f; }
    if (tid < 128) {
        f32x4 hv = *(const f32x4*)&hid[b * CDIM + tid * 4];
        store4_sc(&h0[b * CDIM + tid * 4], hv);
    }
    if (tid < 16) {
        f32x4 rv = *(const f32x4*)&r0[tid * 4];
        store4_sc(&rdv[b * MM + tid * 4], rv);
    }
    DRAIN();
    __syncthreads();
    if (tid == 0) inc_cnt(cntA);

    float c_reg[2][4];
    float bjv[4];
    {
        int jg = jt * 16 + rr;
#pragma unroll
        for (int s = 0; s < 2; ++s)
#pragma unroll
            for (int r = 0; r < 4; ++r) c_reg[s][r] = c0[jg];
        bjv[0] = bias1[jg];        bjv[1] = bias1[512 + jg];
        bjv[2] = bias1[1024 + jg]; bjv[3] = bias1[1536 + jg];
    }

    // wave kb lists: x:{wid,4+wid}  h: base+4i (base 12,13,10,11)  rdv: 8+wid (wid<2)
    const int kbh0 = (wid < 2) ? (12 + wid) : (8 + wid);

    for (int t = 0; t < TT; ++t) {
        const float* hin = (t & 1) ? h1 : h0;
        float* hout      = (t & 1) ? h0 : h1;
        float* op_t      = opart + (size_t)(t & 1) * OPN;
        float* out_t     = out + (size_t)t * BSZ * ODIM;
        const unsigned tgt = 32u * (t + 1);

        // ================= phase A: gates GEMM + LSTM + head partials =================
        {
            if (t == 0) spin_ge(cntA, 32u);   // init h0/rdv visible

            // pre-issue h-fragment loads (IC latency hidden under x-kbs)
            f32x4 pre[4][4];
#pragma unroll
            for (int i = 0; i < 4; ++i) {
                const int kb = kbh0 + 4 * i;
                const float* p = hin + (m0 + row_s) * CDIM + (kb - 10) * 32 + cc;
                load16_sc_async(p, pre[i][0], pre[i][1], pre[i][2], pre[i][3]);
            }

            f32x4 acc[2][4];
#pragma unroll
            for (int s = 0; s < 2; ++s)
#pragma unroll
                for (int g = 0; g < 4; ++g) acc[s][g] = (f32x4){0.f, 0.f, 0.f, 0.f};

            const float* x_t = inp + (size_t)t * BSZ * IDIM;

            // helper macro: stage f[16] for kb, then 24 MFMAs
#define PROC_KB(KB, F)                                                          \
            {                                                                   \
                const int kb_ = (KB);                                           \
                const int boff = ((kb_ * 32 + jt) * 256 + l) * 8;               \
                s16x8 bfh[4], bfl[4];                                           \
                _Pragma("unroll")                                               \
                for (int g = 0; g < 4; ++g) {                                   \
                    bfh[g] = *(const s16x8*)(B1h + boff + g * 512);             \
                    bfl[g] = *(const s16x8*)(B1l + boff + g * 512);             \
                }                                                               \
                s16x8 vh0, vl0, vh1, vl1;                                       \
                _Pragma("unroll")                                               \
                for (int q = 0; q < 8; ++q) {                                   \
                    ush h_, l_;                                                 \
                    split2((F)[q], h_, l_);                                     \
                    vh0[q] = (short)h_; vl0[q] = (short)l_;                     \
                    split2((F)[8 + q], h_, l_);                                 \
                    vh1[q] = (short)h_; vl1[q] = (short)l_;                     \
                }                                                               \
                *(s16x8*)&AH[wid][row_s][cc]     = vh0;                         \
                *(s16x8*)&AH[wid][row_s][cc + 8] = vh1;                         \
                *(s16x8*)&AL[wid][row_s][cc]     = vl0;                         \
                *(s16x8*)&AL[wid][row_s][cc + 8] = vl1;                         \
                s16x8 a0h = *(const s16x8*)&AH[wid][rr][kq];                    \
                s16x8 a0l = *(const s16x8*)&AL[wid][rr][kq];                    \
                s16x8 a1h = *(const s16x8*)&AH[wid][16 + rr][kq];               \
                s16x8 a1l = *(const s16x8*)&AL[wid][16 + rr][kq];               \
                _Pragma("unroll")                                               \
                for (int g = 0; g < 4; ++g) {                                   \
                    acc[0][g] = MFMA(a0h, bfh[g], acc[0][g], 0, 0, 0);          \
                    acc[1][g] = MFMA(a1h, bfh[g], acc[1][g], 0, 0, 0);          \
                    acc[0][g] = MFMA(a0l, bfh[g], acc[0][g], 0, 0, 0);          \
                    acc[1][g] = MFMA(a1l, bfh[g], acc[1][g], 0, 0, 0);          \
                    acc[0][g] = MFMA(a0h, bfl[g], acc[0][g], 0, 0, 0);          \
                    acc[1][g] = MFMA(a1h, bfl[g], acc[1][g], 0, 0, 0);          \
                }                                                               \
            }

            // x-kbs (normal cached loads)
#pragma unroll
            for (int i = 0; i < 2; ++i) {
                const int kb = wid + 4 * i;
                const float* p = x_t + (m0 + row_s) * IDIM + kb * 32 + cc;
                float f[16];
                *(f32x4*)&f[0]  = ((const f32x4*)p)[0];
                *(f32x4*)&f[4]  = ((const f32x4*)p)[1];
                *(f32x4*)&f[8]  = ((const f32x4*)p)[2];
                *(f32x4*)&f[12] = ((const f32x4*)p)[3];
                PROC_KB(kb, f);
            }

            DRAIN();   // h prefetch arrived
            // h-kbs
#pragma unroll
            for (int i = 0; i < 4; ++i) {
                const int kb = kbh0 + 4 * i;
                float f[16];
                *(f32x4*)&f[0]  = pre[i][0];
                *(f32x4*)&f[4]  = pre[i][1];
                *(f32x4*)&f[8]  = pre[i][2];
                *(f32x4*)&f[12] = pre[i][3];
                PROC_KB(kb, f);
            }

            // rdv-kb last (waves 0,1), waits its producers
            if (wid < 2) {
                spin_ge(cntA, tgt);
                const int kb = 8 + wid;
                const float* p = rdv + (m0 + row_s) * MM + (kb - 8) * 32 + cc;
                f32x4 r0q, r1q, r2q, r3q;
                load16_sc_async(p, r0q, r1q, r2q, r3q);
                DRAIN();
                float f[16];
                *(f32x4*)&f[0]  = r0q;
                *(f32x4*)&f[4]  = r1q;
                *(f32x4*)&f[8]  = r2q;
                *(f32x4*)&f[12] = r3q;
                PROC_KB(kb, f);
            }
#undef PROC_KB

            // split-K reduce (scratch aliased -> sync first)
            __syncthreads();
            if (wid >= 2) {
                float* dst = (wid == 2) ? red0 : red1;
#pragma unroll
                for (int s = 0; s < 2; ++s)
#pragma unroll
                    for (int g = 0; g < 4; ++g)
#pragma unroll
                        for (int r = 0; r < 4; ++r)
                            dst[((s * 16 + (l >> 4) * 4 + r) << 6) + (g << 4) + rr] = acc[s][g][r];
            }
            __syncthreads();
            if (wid < 2) {
                const float* src = (wid == 0) ? red0 : red1;
#pragma unroll
                for (int s = 0; s < 2; ++s)
#pragma unroll
                    for (int g = 0; g < 4; ++g)
#pragma unroll
                        for (int r = 0; r < 4; ++r)
                            acc[s][g][r] += src[((s * 16 + (l >> 4) * 4 + r) << 6) + (g << 4) + rr];
            }
            __syncthreads();
            if (wid == 1) {
#pragma unroll
                for (int s = 0; s < 2; ++s)
#pragma unroll
                    for (int g = 0; g < 4; ++g)
#pragma unroll
                        for (int r = 0; r < 4; ++r)
                            red0[((s * 16 + (l >> 4) * 4 + r) << 6) + (g << 4) + rr] = acc[s][g][r];
            }
            __syncthreads();
            if (wid == 0) {
                const int jg = jt * 16 + rr;
#pragma unroll
                for (int s = 0; s < 2; ++s)
#pragma unroll
                    for (int r = 0; r < 4; ++r) {
                        const int row = s * 16 + (l >> 4) * 4 + r;
                        const int ridx = (row << 6) + rr;
                        float gi  = acc[s][0][r] + red0[ridx]       + bjv[0];
                        float gf  = acc[s][1][r] + red0[ridx + 16]  + bjv[1];
                        float gg2 = acc[s][2][r] + red0[ridx + 32]  + bjv[2];
                        float go  = acc[s][3][r] + red0[ridx + 48]  + bjv[3];
                        float cn = sigmoidf_(gf) * c_reg[s][r] + sigmoidf_(gi) * tanhf(gg2);
                        float hn = sigmoidf_(go) * tanhf(cn);
                        c_reg[s][r] = cn;
                        const int b2 = m0 + row;
                        store1_sc(&hout[b2 * CDIM + jg], hn);
                        out_t[b2 * ODIM + jg] = hn;
                        hsl[row * 16 + rr] = hn;
                    }
            }
            __syncthreads();   // hsl ready

            // head partials for this j-slice: opart[(m0+r)*32 + jt][272]
            {
                float* opb = op_t + ((size_t)m0 * 32 + jt) * 272;
#pragma unroll
                for (int cpass = 0; cpass < 2; ++cpass) {
                    const int c = cpass * 256 + tid;
                    if (c < 272) {
                        const f32x4* wp = (const f32x4*)&W2P[(jt * 272 + c) * 16];
                        f32x4 w0 = wp[0], w1 = wp[1], w2 = wp[2], w3 = wp[3];
                        for (int r = 0; r < 32; ++r) {
                            const float* hr = &hsl[r * 16];
                            float a = hr[0]*w0.x + hr[1]*w0.y + hr[2]*w0.z + hr[3]*w0.w
                                    + hr[4]*w1.x + hr[5]*w1.y + hr[6]*w1.z + hr[7]*w1.w
                                    + hr[8]*w2.x + hr[9]*w2.y + hr[10]*w2.z + hr[11]*w2.w
                                    + hr[12]*w3.x + hr[13]*w3.y + hr[14]*w3.z + hr[15]*w3.w;
                            store1_sc(opb + (size_t)r * (32 * 272) + c, a);
                        }
                    }
                }
            }
            DRAIN();
            __syncthreads();
            if (tid == 0) inc_cnt(cntB);
        }

        // ================= phase B: reduce partials + addressing + memory update =================
        {
            spin_ge(cntB, tgt);

            // reduce 32 j-slice partials (contiguous 34 KB for this batch row)
            if (tid < 68) {
                const int c4 = tid * 4;
                const float* base = op_t + ((size_t)b * 32) * 272 + c4;
                f32x4 tot = *(const f32x4*)&bias2[c4];
                f32x4 pp[16];
#pragma unroll
                for (int j = 0; j < 16; ++j) load4_sc_async(base + (size_t)j * 272, pp[j]);
                DRAIN();
#pragma unroll
                for (int j = 0; j < 16; ++j) tot += pp[j];
#pragma unroll
                for (int j = 0; j < 16; ++j) load4_sc_async(base + (size_t)(16 + j) * 272, pp[j]);
                DRAIN();
#pragma unroll
                for (int j = 0; j < 16; ++j) tot += pp[j];
                *(f32x4*)&os_l[c4] = tot;
            }
            __syncthreads();

            for (int head = 0; head < 2; ++head) {
                const int ob = head ? 70 : 0;
                float* wst = head ? ww_s : wr_s;

                float beta = softplusf_(os_l[ob + 64]);
                float gte  = sigmoidf_(os_l[ob + 65]);
                float s0r = os_l[ob + 66], s1r = os_l[ob + 67], s2r = os_l[ob + 68];
                float smx = fmaxf(s0r, fmaxf(s1r, s2r));
                float e0 = expf(s0r - smx), e1 = expf(s1r - smx), e2 = expf(s2r - smx);
                float einv = 1.f / (e0 + e1 + e2);
                float s0 = e0 * einv, s1 = e1 * einv, s2 = e2 * einv;
                float gamma = 1.f + softplusf_(os_l[ob + 69]);

                float simv = -1e30f;
                if (tid < NN) {
                    float dot = 0.f, nm2 = 0.f, nk2 = 0.f;
                    const float* mrow = ms + tid * 65;
#pragma unroll 8
                    for (int m = 0; m < MM; ++m) {
                        float mv = mrow[m] + 1e-16f;
                        float kv = os_l[ob + m] + 1e-16f;
                        dot += mv * kv; nm2 += mv * mv; nk2 += kv * kv;
                    }
                    float nm = fmaxf(sqrtf(nm2), 1e-8f);
                    float nk = fmaxf(sqrtf(nk2), 1e-8f);
                    simv = beta * dot / (nm * nk);
                }
                float v = simv;
#pragma unroll
                for (int off = 32; off; off >>= 1) v = fmaxf(v, __shfl_xor(v, off));
                if ((tid & 63) == 0) red4[tid >> 6] = v;
                __syncthreads();
                float smax = fmaxf(fmaxf(red4[0], red4[1]), fmaxf(red4[2], red4[3]));
                __syncthreads();

                float pv = (tid < NN) ? expf(simv - smax) : 0.f;
                v = pv;
#pragma unroll
                for (int off = 32; off; off >>= 1) v += __shfl_xor(v, off);
                if ((tid & 63) == 0) red4[tid >> 6] = v;
                __syncthreads();
                float psum = red4[0] + red4[1] + red4[2] + red4[3];
                __syncthreads();

                if (tid < NN) {
                    float wc = pv / psum;
                    wgs[tid] = gte * wc + (1.f - gte) * wst[tid];
                }
                __syncthreads();

                float wv_ = 0.f;
                if (tid < NN) {
                    int nl = (tid + NN - 1) & (NN - 1), nr = (tid + 1) & (NN - 1);
                    float wwv = s0 * wgs[nl] + s1 * wgs[tid] + s2 * wgs[nr];
                    wv_ = powf(wwv, gamma);
                }
                v = wv_;
#pragma unroll
                for (int off = 32; off; off >>= 1) v += __shfl_xor(v, off);
                if ((tid & 63) == 0) red4[tid >> 6] = v;
                __syncthreads();
                float wsum = red4[0] + red4[1] + red4[2] + red4[3];
                __syncthreads();

                if (tid < NN) {
                    float wfin = wv_ / (wsum + 1e-16f);
                    wsh[tid] = wfin;
                    wst[tid] = wfin;
                }
                __syncthreads();

                if (head == 0) {
                    // read vector -> rdv (then release A(t+1) consumers ASAP)
                    if (tid < MM) {
                        float r = 0.f;
#pragma unroll 8
                        for (int n = 0; n < NN; ++n) r += wsh[n] * ms[n * 65 + tid];
                        store1_sc(&rdv[b * MM + tid], r);
                        out_t[b * ODIM + CDIM + tid] = r;
                    }
                    if (wid == 0) DRAIN();
                    __syncthreads();
                    if (tid == 0) inc_cnt(cntA);
                } else {
                    if (tid < MM) {
                        esh[tid] = sigmoidf_(os_l[140 + tid]);
                        ash[tid] = os_l[204 + tid];
                    }
                    __syncthreads();
                    for (int i = tid; i < NN * MM / 4; i += 256) {
                        int n = i >> 4, m4 = (i & 15) * 4;
                        float wvn = wsh[n];
#pragma unroll
                        for (int q = 0; q < 4; ++q) {
                            float mv = ms[n * 65 + m4 + q];
                            ms[n * 65 + m4 + q] = mv * (1.f - wvn * esh[m4 + q]) + wvn * ash[m4 + q];
                        }
                    }
                    __syncthreads();
                }
            }
        }
    }
}

extern "C" void kernel_launch(void* const* d_in, const int* in_sizes, int n_in,
                              void* d_out, int out_size, void* d_ws, size_t ws_size,
                              hipStream_t stream) {
    const float* inp      = (const float*)d_in[0];
    const float* hid      = (const float*)d_in[1];
    const float* c0       = (const float*)d_in[2];
    const float* mem_bias = (const float*)d_in[3];
    const float* r0       = (const float*)d_in[4];
    const float* W_ih     = (const float*)d_in[5];
    const float* W_hh     = (const float*)d_in[6];
    const float* b_ih     = (const float*)d_in[7];
    const float* b_hh     = (const float*)d_in[8];
    const float* read_W   = (const float*)d_in[9];
    const float* read_b   = (const float*)d_in[10];
    const float* write_W  = (const float*)d_in[11];
    const float* write_b  = (const float*)d_in[12];
    float* out = (float*)d_out;

    char* p = (char*)d_ws;
    auto alloc = [&](size_t bytes) { char* r = p; p += (bytes + 255) & ~(size_t)255; return r; };
    const size_t nB1 = (size_t)NKB1 * 32 * 4 * 64 * 8;
    ush* B1h = (ush*)alloc(nB1 * 2);
    ush* B1l = (ush*)alloc(nB1 * 2);
    float* bias1 = (float*)alloc(GJ * 4);
    float* W2P   = (float*)alloc((size_t)32 * 272 * 16 * 4);
    float* bias2 = (float*)alloc(272 * 4);
    float* h0    = (float*)alloc((size_t)BSZ * CDIM * 4);
    float* h1    = (float*)alloc((size_t)BSZ * CDIM * 4);
    float* rdv   = (float*)alloc((size_t)BSZ * MM * 4);
    float* opart = (float*)alloc((size_t)2 * BSZ * 32 * 272 * 4);
    unsigned* bar = (unsigned*)alloc(1024 * 4);

    k_packB1<<<2048, 256, 0, stream>>>(W_ih, W_hh, b_ih, b_hh, B1h, B1l, bias1);
    k_packW2P<<<546, 256, 0, stream>>>(read_W, read_b, write_W, write_b, W2P, bias2);
    k_barinit<<<1, 64, 0, stream>>>(bar);

    k_persist<<<dim3(NBLK), dim3(256), 0, stream>>>(
        inp, hid, c0, mem_bias, r0,
        B1h, B1l, bias1, W2P, bias2,
        h0, h1, rdv, opart, out, bar);
}